// Round 6
// baseline (527.514 us; speedup 1.0000x reference)
//
#include <hip/hip_runtime.h>

#define NN 100000
#define EE 1600000
#define DI 128
#define HH 64
#define CO 10
#define GG 1024
#define BSH 7                               // 128 nodes per bucket
#define BNODES (1 << BSH)
#define NB ((NN + BNODES - 1) / BNODES)     // 782 buckets
#define TILE 16384
#define NT ((EE + TILE - 1) / TILE)         // 98 tiles
#define SN (NB * NT)                        // 76636 (bucket,tile) counters
#define SCB 1024
#define NSB ((SN + SCB - 1) / SCB)          // 75 scan blocks

// ---------------- collapsed weights: Wf = W1@W2@W3@Wl; c1,c2,c3 ----------------
__global__ void k_small_mats(const float* __restrict__ W1, const float* __restrict__ W2,
                             const float* __restrict__ W3, const float* __restrict__ Wl,
                             const float* __restrict__ b1, const float* __restrict__ b2,
                             const float* __restrict__ b3,
                             float* __restrict__ Wf, float* __restrict__ cvec) {
    __shared__ float M3l[HH * CO];
    __shared__ float M23l[HH * CO];
    int t = threadIdx.x;
    for (int i = t; i < HH * CO; i += blockDim.x) {
        int r = i / CO, c = i % CO;
        float s = 0.f;
        for (int k = 0; k < HH; ++k) s += W3[r * HH + k] * Wl[k * CO + c];
        M3l[i] = s;
    }
    __syncthreads();
    for (int i = t; i < HH * CO; i += blockDim.x) {
        int r = i / CO, c = i % CO;
        float s = 0.f;
        for (int k = 0; k < HH; ++k) s += W2[r * HH + k] * M3l[k * CO + c];
        M23l[i] = s;
    }
    __syncthreads();
    for (int i = t; i < DI * CO; i += blockDim.x) {
        int r = i / CO, c = i % CO;
        float s = 0.f;
        for (int k = 0; k < HH; ++k) s += W1[r * HH + k] * M23l[k * CO + c];
        Wf[i] = s;
    }
    if (t < CO) {
        float s1 = 0.f, s2 = 0.f, s3 = 0.f;
        for (int k = 0; k < HH; ++k) {
            s1 += b1[k] * M23l[k * CO + t];
            s2 += b2[k] * M3l[k * CO + t];
            s3 += b3[k] * Wl[k * CO + t];
        }
        cvec[t] = s1; cvec[CO + t] = s2; cvec[2 * CO + t] = s3;
    }
}

// ---------------- P1: per-tile bucket histogram (LDS atomics only) ----------------
__global__ __launch_bounds__(256) void k_pcount(const int* __restrict__ col, int* __restrict__ cnt) {
    __shared__ int h[NB];
    for (int i = threadIdx.x; i < NB; i += 256) h[i] = 0;
    __syncthreads();
    int base = blockIdx.x * TILE;
    int end = min(base + TILE, EE);
    for (int e = base + threadIdx.x; e < end; e += 256)
        atomicAdd(&h[col[e] >> BSH], 1);
    __syncthreads();
    for (int i = threadIdx.x; i < NB; i += 256)
        cnt[i * NT + blockIdx.x] = h[i];     // bucket-major layout for scan
}

// ---------------- hierarchical exclusive scan of cnt[SN] (in place) ----------------
__global__ __launch_bounds__(SCB) void k_scanA(int* __restrict__ a, int* __restrict__ bsum) {
    __shared__ int s[SCB];
    int t = threadIdx.x, idx = blockIdx.x * SCB + t;
    int v = (idx < SN) ? a[idx] : 0;
    s[t] = v;
    __syncthreads();
    for (int off = 1; off < SCB; off <<= 1) {
        int u = (t >= off) ? s[t - off] : 0;
        __syncthreads();
        s[t] += u;
        __syncthreads();
    }
    if (idx < SN) a[idx] = s[t] - v;
    if (t == SCB - 1) bsum[blockIdx.x] = s[t];
}
__global__ __launch_bounds__(128) void k_scanB(int* __restrict__ bsum) {
    __shared__ int s[128];
    int t = threadIdx.x;
    int v = (t < NSB) ? bsum[t] : 0;
    s[t] = v;
    __syncthreads();
    for (int off = 1; off < 128; off <<= 1) {
        int u = (t >= off) ? s[t - off] : 0;
        __syncthreads();
        s[t] += u;
        __syncthreads();
    }
    if (t < NSB) bsum[t] = s[t] - v;
}
__global__ __launch_bounds__(SCB) void k_scanC(int* __restrict__ a, const int* __restrict__ bsum) {
    int idx = blockIdx.x * SCB + threadIdx.x;
    if (idx < SN) a[idx] += bsum[blockIdx.x];
}

// ---------------- P3: scatter edges bucket-major; packed (row<<7)|(col&127) ----------------
__global__ __launch_bounds__(256) void k_pscatter(const int* __restrict__ row, const int* __restrict__ col,
                                                  const int* __restrict__ S, unsigned* __restrict__ ebuf) {
    __shared__ int ofs[NB];
    for (int i = threadIdx.x; i < NB; i += 256) ofs[i] = S[i * NT + blockIdx.x];
    __syncthreads();
    int base = blockIdx.x * TILE;
    int end = min(base + TILE, EE);
    for (int e = base + threadIdx.x; e < end; e += 256) {
        int c = col[e], r = row[e];
        int pos = atomicAdd(&ofs[c >> BSH], 1);
        ebuf[pos] = ((unsigned)r << BSH) | (unsigned)(c & (BNODES - 1));
    }
}

// ---------------- per-bucket degree -> dinv (LDS histogram) ----------------
__global__ __launch_bounds__(256) void k_bdeg(const unsigned* __restrict__ ebuf, const int* __restrict__ S,
                                              float* __restrict__ dinv) {
    __shared__ int dg[BNODES];
    int b = blockIdx.x;
    if (threadIdx.x < BNODES) dg[threadIdx.x] = 0;
    __syncthreads();
    int beg = S[b * NT];
    int end = (b + 1 < NB) ? S[(b + 1) * NT] : EE;
    for (int e = beg + threadIdx.x; e < end; e += 256)
        atomicAdd(&dg[ebuf[e] & (BNODES - 1)], 1);
    __syncthreads();
    int n = (b << BSH) + threadIdx.x;
    if (threadIdx.x < BNODES && n < NN)
        dinv[n] = rsqrtf((float)(dg[threadIdx.x] + 1));   // +1 self loop
}

// ---------------- graph boundaries via binary search (batch sorted) ----------------
__global__ void k_gstart(const int* __restrict__ batch, int* __restrict__ gstart) {
    int g = blockIdx.x * blockDim.x + threadIdx.x;
    if (g > GG) return;
    int lo = 0, hi = NN;
    while (lo < hi) { int mid = (lo + hi) >> 1; if (batch[mid] < g) lo = mid + 1; else hi = mid; }
    gstart[g] = lo;
}

// ---------------- a0 = (X @ Wf) * dinv ----------------
__global__ __launch_bounds__(256) void k_xw(const float* __restrict__ x, const float* __restrict__ Wf,
                                            const float* __restrict__ dinv,
                                            float* __restrict__ as_) {
    __shared__ float sWf[DI * CO];
    for (int i = threadIdx.x; i < DI * CO; i += blockDim.x) sWf[i] = Wf[i];
    __syncthreads();
    int n = blockIdx.x * blockDim.x + threadIdx.x;
    if (n >= NN) return;
    float acc[CO];
#pragma unroll
    for (int c = 0; c < CO; ++c) acc[c] = 0.f;
    const float4* xr = (const float4*)(x + (size_t)n * DI);
#pragma unroll 4
    for (int d4 = 0; d4 < DI / 4; ++d4) {
        float4 v = xr[d4];
        int d = d4 * 4;
#pragma unroll
        for (int c = 0; c < CO; ++c)
            acc[c] += v.x * sWf[(d + 0) * CO + c] + v.y * sWf[(d + 1) * CO + c]
                    + v.z * sWf[(d + 2) * CO + c] + v.w * sWf[(d + 3) * CO + c];
    }
    float di = dinv[n];
#pragma unroll
    for (int c = 0; c < CO; ++c) as_[(size_t)n * CO + c] = acc[c] * di;
}

// ---------------- propagation round: one block per bucket, LDS accumulate ----------------
// src rows pre-scaled by dinv[src]; y = dinv*(sum+self)+c; non-final rounds pre-scale by dinv.
template <int FINAL>
__global__ __launch_bounds__(256) void k_round(const unsigned* __restrict__ ebuf, const int* __restrict__ S,
                                               const float* __restrict__ src, const float* __restrict__ dinv,
                                               const float* __restrict__ cvec, int coff,
                                               float* __restrict__ dst) {
    __shared__ float acc[BNODES * CO];   // 5 KB
    for (int i = threadIdx.x; i < BNODES * CO; i += 256) acc[i] = 0.f;
    __syncthreads();
    int b = blockIdx.x;
    int beg = S[b * NT];
    int end = (b + 1 < NB) ? S[(b + 1) * NT] : EE;
    for (int e = beg + threadIdx.x; e < end; e += 256) {
        unsigned p = ebuf[e];
        int r = (int)(p >> BSH);
        int ln = (int)(p & (BNODES - 1));
        const float2* sp = (const float2*)(src + (size_t)r * CO);
        float2 a0 = sp[0], a1 = sp[1], a2 = sp[2], a3 = sp[3], a4 = sp[4];
        float* A = &acc[ln * CO];
        atomicAdd(A + 0, a0.x); atomicAdd(A + 1, a0.y);
        atomicAdd(A + 2, a1.x); atomicAdd(A + 3, a1.y);
        atomicAdd(A + 4, a2.x); atomicAdd(A + 5, a2.y);
        atomicAdd(A + 6, a3.x); atomicAdd(A + 7, a3.y);
        atomicAdd(A + 8, a4.x); atomicAdd(A + 9, a4.y);
    }
    __syncthreads();
    int nb0 = b << BSH;
    for (int i = threadIdx.x; i < BNODES * CO; i += 256) {
        int ln = i / CO, ch = i % CO;
        int n = nb0 + ln;
        if (n < NN) {
            float di = dinv[n];
            float y = di * (acc[i] + src[(size_t)n * CO + ch]) + cvec[coff + ch];
            dst[(size_t)n * CO + ch] = FINAL ? y : y * di;
        }
    }
}

// ---------------- mean-pool per graph + bl; one wave per graph ----------------
__global__ __launch_bounds__(64) void k_pool(const float* __restrict__ h,
                                             const int* __restrict__ gstart,
                                             const float* __restrict__ bl,
                                             float* __restrict__ out) {
    int g = blockIdx.x;
    int beg = gstart[g], end = gstart[g + 1];
    int l = threadIdx.x;
    float acc[CO];
#pragma unroll
    for (int c = 0; c < CO; ++c) acc[c] = 0.f;
    for (int n = beg + l; n < end; n += 64) {
        const float2* sp = (const float2*)(h + (size_t)n * CO);
        float2 a = sp[0], b2 = sp[1], c2 = sp[2], d = sp[3], f = sp[4];
        acc[0] += a.x; acc[1] += a.y; acc[2] += b2.x; acc[3] += b2.y; acc[4] += c2.x;
        acc[5] += c2.y; acc[6] += d.x; acc[7] += d.y; acc[8] += f.x; acc[9] += f.y;
    }
#pragma unroll
    for (int m = 1; m < 64; m <<= 1) {
#pragma unroll
        for (int c = 0; c < CO; ++c) acc[c] += __shfl_xor(acc[c], m, 64);
    }
    if (l == 0) {
        float cf = fmaxf((float)(end - beg), 1.f);
#pragma unroll
        for (int c = 0; c < CO; ++c) out[(size_t)g * CO + c] = acc[c] / cf + bl[c];
    }
}

extern "C" void kernel_launch(void* const* d_in, const int* in_sizes, int n_in,
                              void* d_out, int out_size, void* d_ws, size_t ws_size,
                              hipStream_t stream) {
    const float* x    = (const float*)d_in[0];
    const int*   ei   = (const int*)d_in[1];
    const int*   batch= (const int*)d_in[2];
    const float* W1   = (const float*)d_in[3];
    const float* b1   = (const float*)d_in[4];
    const float* W2   = (const float*)d_in[5];
    const float* b2   = (const float*)d_in[6];
    const float* W3   = (const float*)d_in[7];
    const float* b3   = (const float*)d_in[8];
    const float* Wl   = (const float*)d_in[9];
    const float* bl   = (const float*)d_in[10];
    float* out = (float*)d_out;

    const int* row = ei;        // edge_index[0]
    const int* col = ei + EE;   // edge_index[1]

    float* ws = (float*)d_ws;
    size_t off = 0;
    auto alloc = [&](size_t elems) { size_t cur = off; off += (elems + 63) & ~(size_t)63; return cur; };
    float*    Wf     = ws + alloc(DI * CO);
    float*    cvec   = ws + alloc(3 * CO);
    float*    dinv   = ws + alloc(NN);
    int*      S      = (int*)(ws + alloc(SN));        // counts -> exclusive offsets
    int*      bsum   = (int*)(ws + alloc(128));
    unsigned* ebuf   = (unsigned*)(ws + alloc(EE));   // packed (row<<7)|local
    float*    as_    = ws + alloc((size_t)NN * CO);
    float*    bbuf   = ws + alloc((size_t)NN * CO);
    int*      gstart = (int*)(ws + alloc(GG + 1));
    (void)ws_size; (void)in_sizes; (void)n_in; (void)out_size;

    const int BT = 256;
    int gN = (NN + BT - 1) / BT;

    hipLaunchKernelGGL(k_small_mats, dim3(1), dim3(256), 0, stream, W1, W2, W3, Wl, b1, b2, b3, Wf, cvec);
    hipLaunchKernelGGL(k_pcount,   dim3(NT),  dim3(256), 0, stream, col, S);
    hipLaunchKernelGGL(k_scanA,    dim3(NSB), dim3(SCB), 0, stream, S, bsum);
    hipLaunchKernelGGL(k_scanB,    dim3(1),   dim3(128), 0, stream, bsum);
    hipLaunchKernelGGL(k_scanC,    dim3(NSB), dim3(SCB), 0, stream, S, bsum);
    hipLaunchKernelGGL(k_pscatter, dim3(NT),  dim3(256), 0, stream, row, col, S, ebuf);
    hipLaunchKernelGGL(k_bdeg,     dim3(NB),  dim3(256), 0, stream, ebuf, S, dinv);
    hipLaunchKernelGGL(k_gstart,   dim3((GG + 1 + BT - 1) / BT), dim3(BT), 0, stream, batch, gstart);
    hipLaunchKernelGGL(k_xw,       dim3(gN),  dim3(BT), 0, stream, x, Wf, dinv, as_);

    hipLaunchKernelGGL((k_round<0>), dim3(NB), dim3(256), 0, stream, ebuf, S, as_,  dinv, cvec, 0,      bbuf);
    hipLaunchKernelGGL((k_round<0>), dim3(NB), dim3(256), 0, stream, ebuf, S, bbuf, dinv, cvec, CO,     as_);
    hipLaunchKernelGGL((k_round<1>), dim3(NB), dim3(256), 0, stream, ebuf, S, as_,  dinv, cvec, 2 * CO, bbuf);

    hipLaunchKernelGGL(k_pool, dim3(GG), dim3(64), 0, stream, bbuf, gstart, bl, out);
}

// Round 7
// 299.532 us; speedup vs baseline: 1.7611x; 1.7611x over previous
//
#include <hip/hip_runtime.h>

#define NN 100000
#define EE 1600000
#define DI 128
#define HH 64
#define CO 10
#define PAD 12                              // padded row stride (48B)
#define GG 1024
#define BSH 7                               // 128 nodes per bucket
#define BNODES (1 << BSH)
#define NB ((NN + BNODES - 1) / BNODES)     // 782 buckets
#define TILE 16384
#define NT ((EE + TILE - 1) / TILE)         // 98 tiles
#define SN (NB * NT)                        // 76636 (bucket,tile) counters
#define SCB 1024
#define NSB ((SN + SCB - 1) / SCB)          // 75 scan blocks
#define LPN 8                               // lanes per node in gather

// ---------------- collapsed weights: Wf = W1@W2@W3@Wl; c1,c2,c3 ----------------
__global__ void k_small_mats(const float* __restrict__ W1, const float* __restrict__ W2,
                             const float* __restrict__ W3, const float* __restrict__ Wl,
                             const float* __restrict__ b1, const float* __restrict__ b2,
                             const float* __restrict__ b3,
                             float* __restrict__ Wf, float* __restrict__ cvec) {
    __shared__ float M3l[HH * CO];
    __shared__ float M23l[HH * CO];
    int t = threadIdx.x;
    for (int i = t; i < HH * CO; i += blockDim.x) {
        int r = i / CO, c = i % CO;
        float s = 0.f;
        for (int k = 0; k < HH; ++k) s += W3[r * HH + k] * Wl[k * CO + c];
        M3l[i] = s;
    }
    __syncthreads();
    for (int i = t; i < HH * CO; i += blockDim.x) {
        int r = i / CO, c = i % CO;
        float s = 0.f;
        for (int k = 0; k < HH; ++k) s += W2[r * HH + k] * M3l[k * CO + c];
        M23l[i] = s;
    }
    __syncthreads();
    for (int i = t; i < DI * CO; i += blockDim.x) {
        int r = i / CO, c = i % CO;
        float s = 0.f;
        for (int k = 0; k < HH; ++k) s += W1[r * HH + k] * M23l[k * CO + c];
        Wf[i] = s;
    }
    if (t < CO) {
        float s1 = 0.f, s2 = 0.f, s3 = 0.f;
        for (int k = 0; k < HH; ++k) {
            s1 += b1[k] * M23l[k * CO + t];
            s2 += b2[k] * M3l[k * CO + t];
            s3 += b3[k] * Wl[k * CO + t];
        }
        cvec[t] = s1; cvec[CO + t] = s2; cvec[2 * CO + t] = s3;
    }
}

// ---------------- P1: per-tile bucket histogram (LDS atomics) ----------------
__global__ __launch_bounds__(256) void k_pcount(const int* __restrict__ col, int* __restrict__ cnt) {
    __shared__ int h[NB];
    for (int i = threadIdx.x; i < NB; i += 256) h[i] = 0;
    __syncthreads();
    int base = blockIdx.x * TILE;
    int end = min(base + TILE, EE);
    for (int e = base + threadIdx.x; e < end; e += 256)
        atomicAdd(&h[__builtin_nontemporal_load(&col[e]) >> BSH], 1);
    __syncthreads();
    for (int i = threadIdx.x; i < NB; i += 256)
        cnt[i * NT + blockIdx.x] = h[i];     // bucket-major for scan
}

// ---------------- hierarchical exclusive scan of cnt[SN] (in place) ----------------
__global__ __launch_bounds__(SCB) void k_scanA(int* __restrict__ a, int* __restrict__ bsum) {
    __shared__ int s[SCB];
    int t = threadIdx.x, idx = blockIdx.x * SCB + t;
    int v = (idx < SN) ? a[idx] : 0;
    s[t] = v;
    __syncthreads();
    for (int off = 1; off < SCB; off <<= 1) {
        int u = (t >= off) ? s[t - off] : 0;
        __syncthreads();
        s[t] += u;
        __syncthreads();
    }
    if (idx < SN) a[idx] = s[t] - v;
    if (t == SCB - 1) bsum[blockIdx.x] = s[t];
}
__global__ __launch_bounds__(128) void k_scanB(int* __restrict__ bsum) {
    __shared__ int s[128];
    int t = threadIdx.x;
    int v = (t < NSB) ? bsum[t] : 0;
    s[t] = v;
    __syncthreads();
    for (int off = 1; off < 128; off <<= 1) {
        int u = (t >= off) ? s[t - off] : 0;
        __syncthreads();
        s[t] += u;
        __syncthreads();
    }
    if (t < NSB) bsum[t] = s[t] - v;
}
__global__ __launch_bounds__(SCB) void k_scanC(int* __restrict__ a, const int* __restrict__ bsum) {
    int idx = blockIdx.x * SCB + threadIdx.x;
    if (idx < SN) a[idx] += bsum[blockIdx.x];
}

// ---------------- P3: scatter edges bucket-major; packed (row<<7)|(col&127) ----------------
__global__ __launch_bounds__(256) void k_pscatter(const int* __restrict__ row, const int* __restrict__ col,
                                                  const int* __restrict__ S, unsigned* __restrict__ ebuf) {
    __shared__ int ofs[NB];
    for (int i = threadIdx.x; i < NB; i += 256) ofs[i] = S[i * NT + blockIdx.x];
    __syncthreads();
    int base = blockIdx.x * TILE;
    int end = min(base + TILE, EE);
    for (int e = base + threadIdx.x; e < end; e += 256) {
        int c = __builtin_nontemporal_load(&col[e]);
        int r = __builtin_nontemporal_load(&row[e]);
        int pos = atomicAdd(&ofs[c >> BSH], 1);
        ebuf[pos] = ((unsigned)r << BSH) | (unsigned)(c & (BNODES - 1));
    }
}

// ---------------- per-bucket counting sort -> full CSR + dinv (zero global atomics) ----------------
__global__ __launch_bounds__(256) void k_bsort(const unsigned* __restrict__ ebuf, const int* __restrict__ S,
                                               int* __restrict__ srcIdx, int* __restrict__ rowptr_end,
                                               float* __restrict__ dinv) {
    __shared__ int cnt[BNODES];
    __shared__ int s[BNODES];
    __shared__ int ofs[BNODES];
    int t = threadIdx.x;
    int b = blockIdx.x;
    if (t < BNODES) cnt[t] = 0;
    __syncthreads();
    int beg = S[b * NT];
    int end = (b + 1 < NB) ? S[(b + 1) * NT] : EE;
    for (int e = beg + t; e < end; e += 256)
        atomicAdd(&cnt[__builtin_nontemporal_load(&ebuf[e]) & (BNODES - 1)], 1);
    __syncthreads();
    int v = 0;
    if (t < BNODES) { v = cnt[t]; s[t] = v; }
    __syncthreads();
    for (int off = 1; off < BNODES; off <<= 1) {
        int u = 0;
        if (t < BNODES && t >= off) u = s[t - off];
        __syncthreads();
        if (t < BNODES) s[t] += u;
        __syncthreads();
    }
    if (t < BNODES) {
        int n = (b << BSH) + t;
        if (n < NN) {
            dinv[n] = rsqrtf((float)(v + 1));        // +1 self loop
            rowptr_end[n] = beg + s[t];              // inclusive global end offset
        }
        ofs[t] = beg + s[t] - v;                     // exclusive start
    }
    __syncthreads();
    for (int e = beg + t; e < end; e += 256) {
        unsigned p = __builtin_nontemporal_load(&ebuf[e]);
        int pos = atomicAdd(&ofs[p & (BNODES - 1)], 1);
        srcIdx[pos] = (int)(p >> BSH);
    }
}

// ---------------- graph boundaries via binary search (batch sorted) ----------------
__global__ void k_gstart(const int* __restrict__ batch, int* __restrict__ gstart) {
    int g = blockIdx.x * blockDim.x + threadIdx.x;
    if (g > GG) return;
    int lo = 0, hi = NN;
    while (lo < hi) { int mid = (lo + hi) >> 1; if (batch[mid] < g) lo = mid + 1; else hi = mid; }
    gstart[g] = lo;
}

// ---------------- a0 = (X @ Wf) * dinv ; padded rows ----------------
__global__ __launch_bounds__(256) void k_xw(const float* __restrict__ x, const float* __restrict__ Wf,
                                            const float* __restrict__ dinv,
                                            float* __restrict__ as_) {
    __shared__ float sWf[DI * CO];
    for (int i = threadIdx.x; i < DI * CO; i += blockDim.x) sWf[i] = Wf[i];
    __syncthreads();
    int n = blockIdx.x * blockDim.x + threadIdx.x;
    if (n >= NN) return;
    float acc[CO];
#pragma unroll
    for (int c = 0; c < CO; ++c) acc[c] = 0.f;
    const float4* xr = (const float4*)(x + (size_t)n * DI);
#pragma unroll 4
    for (int d4 = 0; d4 < DI / 4; ++d4) {
        float4 v = xr[d4];
        int d = d4 * 4;
#pragma unroll
        for (int c = 0; c < CO; ++c)
            acc[c] += v.x * sWf[(d + 0) * CO + c] + v.y * sWf[(d + 1) * CO + c]
                    + v.z * sWf[(d + 2) * CO + c] + v.w * sWf[(d + 3) * CO + c];
    }
    float di = dinv[n];
    float* o = as_ + (size_t)n * PAD;
    ((float4*)o)[0] = make_float4(acc[0] * di, acc[1] * di, acc[2] * di, acc[3] * di);
    ((float4*)o)[1] = make_float4(acc[4] * di, acc[5] * di, acc[6] * di, acc[7] * di);
    ((float2*)(o + 8))[0] = make_float2(acc[8] * di, acc[9] * di);
}

// ---------------- gather round: register accumulate + shfl reduce ----------------
// src rows pre-scaled by dinv[src]; y = dinv[n]*(sum+self)+c; non-final pre-scale by dinv[n].
template <int FINAL>
__global__ __launch_bounds__(256) void k_gather(const int* __restrict__ rowptr_end,
                                                const int* __restrict__ srcIdx,
                                                const float* __restrict__ src,
                                                const float* __restrict__ dinv,
                                                const float* __restrict__ cvec, int coff,
                                                float* __restrict__ dst) {
    int gid = blockIdx.x * blockDim.x + threadIdx.x;
    int n = gid / LPN;
    int l = threadIdx.x & (LPN - 1);
    if (n >= NN) return;
    int beg = (n == 0) ? 0 : rowptr_end[n - 1];
    int end = rowptr_end[n];
    float acc[CO];
#pragma unroll
    for (int c = 0; c < CO; ++c) acc[c] = 0.f;
    for (int e = beg + l; e < end; e += LPN) {
        int s = __builtin_nontemporal_load(&srcIdx[e]);
        const float* sp = src + (size_t)s * PAD;
        float4 a = ((const float4*)sp)[0];
        float4 b = ((const float4*)sp)[1];
        float2 c2 = ((const float2*)(sp + 8))[0];
        acc[0] += a.x; acc[1] += a.y; acc[2] += a.z; acc[3] += a.w;
        acc[4] += b.x; acc[5] += b.y; acc[6] += b.z; acc[7] += b.w;
        acc[8] += c2.x; acc[9] += c2.y;
    }
#pragma unroll
    for (int m = 1; m < LPN; m <<= 1) {
#pragma unroll
        for (int c = 0; c < CO; ++c) acc[c] += __shfl_xor(acc[c], m, 64);
    }
    if (l == 0) {
        float di = dinv[n];
        const float* selfp = src + (size_t)n * PAD;
        float o[CO];
#pragma unroll
        for (int c = 0; c < CO; ++c) {
            float y = di * (acc[c] + selfp[c]) + cvec[coff + c];
            o[c] = FINAL ? y : y * di;
        }
        float* dp = dst + (size_t)n * PAD;
        ((float4*)dp)[0] = make_float4(o[0], o[1], o[2], o[3]);
        ((float4*)dp)[1] = make_float4(o[4], o[5], o[6], o[7]);
        ((float2*)(dp + 8))[0] = make_float2(o[8], o[9]);
    }
}

// ---------------- mean-pool per graph + bl; one wave per graph ----------------
__global__ __launch_bounds__(64) void k_pool(const float* __restrict__ h,
                                             const int* __restrict__ gstart,
                                             const float* __restrict__ bl,
                                             float* __restrict__ out) {
    int g = blockIdx.x;
    int beg = gstart[g], end = gstart[g + 1];
    int l = threadIdx.x;
    float acc[CO];
#pragma unroll
    for (int c = 0; c < CO; ++c) acc[c] = 0.f;
    for (int n = beg + l; n < end; n += 64) {
        const float* sp = h + (size_t)n * PAD;
        float4 a = ((const float4*)sp)[0];
        float4 b = ((const float4*)sp)[1];
        float2 c2 = ((const float2*)(sp + 8))[0];
        acc[0] += a.x; acc[1] += a.y; acc[2] += a.z; acc[3] += a.w;
        acc[4] += b.x; acc[5] += b.y; acc[6] += b.z; acc[7] += b.w;
        acc[8] += c2.x; acc[9] += c2.y;
    }
#pragma unroll
    for (int m = 1; m < 64; m <<= 1) {
#pragma unroll
        for (int c = 0; c < CO; ++c) acc[c] += __shfl_xor(acc[c], m, 64);
    }
    if (l == 0) {
        float cf = fmaxf((float)(end - beg), 1.f);
#pragma unroll
        for (int c = 0; c < CO; ++c) out[(size_t)g * CO + c] = acc[c] / cf + bl[c];
    }
}

extern "C" void kernel_launch(void* const* d_in, const int* in_sizes, int n_in,
                              void* d_out, int out_size, void* d_ws, size_t ws_size,
                              hipStream_t stream) {
    const float* x    = (const float*)d_in[0];
    const int*   ei   = (const int*)d_in[1];
    const int*   batch= (const int*)d_in[2];
    const float* W1   = (const float*)d_in[3];
    const float* b1   = (const float*)d_in[4];
    const float* W2   = (const float*)d_in[5];
    const float* b2   = (const float*)d_in[6];
    const float* W3   = (const float*)d_in[7];
    const float* b3   = (const float*)d_in[8];
    const float* Wl   = (const float*)d_in[9];
    const float* bl   = (const float*)d_in[10];
    float* out = (float*)d_out;

    const int* row = ei;        // edge_index[0]
    const int* col = ei + EE;   // edge_index[1]

    float* ws = (float*)d_ws;
    size_t off = 0;
    auto alloc = [&](size_t elems) { size_t cur = off; off += (elems + 63) & ~(size_t)63; return cur; };
    float*    Wf      = ws + alloc(DI * CO);
    float*    cvec    = ws + alloc(3 * CO);
    float*    dinv    = ws + alloc(NN);
    int*      S       = (int*)(ws + alloc(SN));
    int*      bsum    = (int*)(ws + alloc(128));
    unsigned* ebuf    = (unsigned*)(ws + alloc(EE));
    int*      srcIdx  = (int*)(ws + alloc(EE));
    int*      rowptr  = (int*)(ws + alloc(NN));          // inclusive end offsets
    float*    as_     = ws + alloc((size_t)NN * PAD);
    float*    bbuf    = ws + alloc((size_t)NN * PAD);
    int*      gstart  = (int*)(ws + alloc(GG + 1));
    (void)ws_size; (void)in_sizes; (void)n_in; (void)out_size;

    const int BT = 256;
    int gN = (NN + BT - 1) / BT;
    int gNL = ((NN * LPN) + BT - 1) / BT;

    hipLaunchKernelGGL(k_small_mats, dim3(1), dim3(256), 0, stream, W1, W2, W3, Wl, b1, b2, b3, Wf, cvec);
    hipLaunchKernelGGL(k_pcount,   dim3(NT),  dim3(256), 0, stream, col, S);
    hipLaunchKernelGGL(k_scanA,    dim3(NSB), dim3(SCB), 0, stream, S, bsum);
    hipLaunchKernelGGL(k_scanB,    dim3(1),   dim3(128), 0, stream, bsum);
    hipLaunchKernelGGL(k_scanC,    dim3(NSB), dim3(SCB), 0, stream, S, bsum);
    hipLaunchKernelGGL(k_pscatter, dim3(NT),  dim3(256), 0, stream, row, col, S, ebuf);
    hipLaunchKernelGGL(k_bsort,    dim3(NB),  dim3(256), 0, stream, ebuf, S, srcIdx, rowptr, dinv);
    hipLaunchKernelGGL(k_gstart,   dim3((GG + 1 + BT - 1) / BT), dim3(BT), 0, stream, batch, gstart);
    hipLaunchKernelGGL(k_xw,       dim3(gN),  dim3(BT), 0, stream, x, Wf, dinv, as_);

    hipLaunchKernelGGL((k_gather<0>), dim3(gNL), dim3(BT), 0, stream, rowptr, srcIdx, as_,  dinv, cvec, 0,      bbuf);
    hipLaunchKernelGGL((k_gather<0>), dim3(gNL), dim3(BT), 0, stream, rowptr, srcIdx, bbuf, dinv, cvec, CO,     as_);
    hipLaunchKernelGGL((k_gather<1>), dim3(gNL), dim3(BT), 0, stream, rowptr, srcIdx, as_,  dinv, cvec, 2 * CO, bbuf);

    hipLaunchKernelGGL(k_pool, dim3(GG), dim3(64), 0, stream, bbuf, gstart, bl, out);
}

// Round 9
// 283.729 us; speedup vs baseline: 1.8592x; 1.0557x over previous
//
#include <hip/hip_runtime.h>

#define NN 100000
#define EE 1600000
#define DI 128
#define HH 64
#define CO 10
#define PADF 12                             // floats per staged row (48B)
#define GG 1024
#define BSH 7                               // 128 nodes per bucket
#define BNODES (1 << BSH)
#define NB ((NN + BNODES - 1) / BNODES)     // 782 buckets
#define TILE 16384
#define NT ((EE + TILE - 1) / TILE)         // 98 tiles
#define SN (NB * NT)                        // (bucket,tile) counters
#define SCB 1024
#define NSB ((SN + SCB - 1) / SCB)
#define LPN 4                               // lanes per node in gather

// ---- fused front: blocks [0,NT) bucket-histogram; block NT collapsed weights; rest gstart ----
__global__ __launch_bounds__(256) void k_front(const int* __restrict__ col,
                                               const float* __restrict__ W1, const float* __restrict__ W2,
                                               const float* __restrict__ W3, const float* __restrict__ Wl,
                                               const float* __restrict__ b1, const float* __restrict__ b2,
                                               const float* __restrict__ b3,
                                               const int* __restrict__ batch,
                                               int* __restrict__ cnt, float* __restrict__ Wf,
                                               float* __restrict__ cvec, int* __restrict__ gstart) {
    __shared__ float smem[1280];
    int bid = blockIdx.x, t = threadIdx.x;
    if (bid < NT) {
        int* h = (int*)smem;
        for (int i = t; i < NB; i += 256) h[i] = 0;
        __syncthreads();
        int base = bid * TILE, end = min(base + TILE, EE);
        for (int e = base + t; e < end; e += 256)
            atomicAdd(&h[__builtin_nontemporal_load(&col[e]) >> BSH], 1);
        __syncthreads();
        for (int i = t; i < NB; i += 256) cnt[i * NT + bid] = h[i];
    } else if (bid == NT) {
        float* M3l = smem;           // 640
        float* M23l = smem + 640;    // 640
        for (int i = t; i < HH * CO; i += 256) {
            int r = i / CO, c = i % CO;
            float s = 0.f;
            for (int k = 0; k < HH; ++k) s += W3[r * HH + k] * Wl[k * CO + c];
            M3l[i] = s;
        }
        __syncthreads();
        for (int i = t; i < HH * CO; i += 256) {
            int r = i / CO, c = i % CO;
            float s = 0.f;
            for (int k = 0; k < HH; ++k) s += W2[r * HH + k] * M3l[k * CO + c];
            M23l[i] = s;
        }
        __syncthreads();
        for (int i = t; i < DI * CO; i += 256) {
            int r = i / CO, c = i % CO;
            float s = 0.f;
            for (int k = 0; k < HH; ++k) s += W1[r * HH + k] * M23l[k * CO + c];
            Wf[i] = s;
        }
        if (t < CO) {
            float s1 = 0.f, s2 = 0.f, s3 = 0.f;
            for (int k = 0; k < HH; ++k) {
                s1 += b1[k] * M23l[k * CO + t];
                s2 += b2[k] * M3l[k * CO + t];
                s3 += b3[k] * Wl[k * CO + t];
            }
            cvec[t] = s1; cvec[CO + t] = s2; cvec[2 * CO + t] = s3;
        }
    } else {
        int g = (bid - NT - 1) * 256 + t;
        if (g <= GG) {
            int lo = 0, hi = NN;
            while (lo < hi) { int mid = (lo + hi) >> 1; if (batch[mid] < g) lo = mid + 1; else hi = mid; }
            gstart[g] = lo;
        }
    }
}

// ---------------- hierarchical exclusive scan of cnt[SN] (in place) ----------------
__global__ __launch_bounds__(SCB) void k_scanA(int* __restrict__ a, int* __restrict__ bsum) {
    __shared__ int s[SCB];
    int t = threadIdx.x, idx = blockIdx.x * SCB + t;
    int v = (idx < SN) ? a[idx] : 0;
    s[t] = v;
    __syncthreads();
    for (int off = 1; off < SCB; off <<= 1) {
        int u = (t >= off) ? s[t - off] : 0;
        __syncthreads();
        s[t] += u;
        __syncthreads();
    }
    if (idx < SN) a[idx] = s[t] - v;
    if (t == SCB - 1) bsum[blockIdx.x] = s[t];
}
__global__ __launch_bounds__(128) void k_scanB(int* __restrict__ bsum) {
    __shared__ int s[128];
    int t = threadIdx.x;
    int v = (t < NSB) ? bsum[t] : 0;
    s[t] = v;
    __syncthreads();
    for (int off = 1; off < 128; off <<= 1) {
        int u = (t >= off) ? s[t - off] : 0;
        __syncthreads();
        s[t] += u;
        __syncthreads();
    }
    if (t < NSB) bsum[t] = s[t] - v;
}
__global__ __launch_bounds__(SCB) void k_scanC(int* __restrict__ a, const int* __restrict__ bsum) {
    int idx = blockIdx.x * SCB + threadIdx.x;
    if (idx < SN) a[idx] += bsum[blockIdx.x];
}

// ---------------- scatter edges bucket-major; packed (row<<7)|(col&127) ----------------
__global__ __launch_bounds__(256) void k_pscatter(const int* __restrict__ row, const int* __restrict__ col,
                                                  const int* __restrict__ S, unsigned* __restrict__ ebuf) {
    __shared__ int ofs[NB];
    for (int i = threadIdx.x; i < NB; i += 256) ofs[i] = S[i * NT + blockIdx.x];
    __syncthreads();
    int base = blockIdx.x * TILE;
    int end = min(base + TILE, EE);
    for (int e = base + threadIdx.x; e < end; e += 256) {
        int c = __builtin_nontemporal_load(&col[e]);
        int r = __builtin_nontemporal_load(&row[e]);
        int pos = atomicAdd(&ofs[c >> BSH], 1);
        ebuf[pos] = ((unsigned)r << BSH) | (unsigned)(c & (BNODES - 1));
    }
}

// ---------------- per-bucket counting sort -> CSR + dinv (zero global atomics) ----------------
__global__ __launch_bounds__(256) void k_bsort(const unsigned* __restrict__ ebuf, const int* __restrict__ S,
                                               int* __restrict__ srcIdx, int* __restrict__ rowptr_end,
                                               float* __restrict__ dinv) {
    __shared__ int cnt[BNODES];
    __shared__ int s[BNODES];
    __shared__ int ofs[BNODES];
    int t = threadIdx.x;
    int b = blockIdx.x;
    if (t < BNODES) cnt[t] = 0;
    __syncthreads();
    int beg = S[b * NT];
    int end = (b + 1 < NB) ? S[(b + 1) * NT] : EE;
    for (int e = beg + t; e < end; e += 256)
        atomicAdd(&cnt[__builtin_nontemporal_load(&ebuf[e]) & (BNODES - 1)], 1);
    __syncthreads();
    int v = 0;
    if (t < BNODES) { v = cnt[t]; s[t] = v; }
    __syncthreads();
    for (int off = 1; off < BNODES; off <<= 1) {
        int u = 0;
        if (t < BNODES && t >= off) u = s[t - off];
        __syncthreads();
        if (t < BNODES) s[t] += u;
        __syncthreads();
    }
    if (t < BNODES) {
        int n = (b << BSH) + t;
        if (n < NN) {
            dinv[n] = rsqrtf((float)(v + 1));        // +1 self loop
            rowptr_end[n] = beg + s[t];              // inclusive end
        }
        ofs[t] = beg + s[t] - v;                     // exclusive start
    }
    __syncthreads();
    for (int e = beg + t; e < end; e += 256) {
        unsigned p = __builtin_nontemporal_load(&ebuf[e]);
        int pos = atomicAdd(&ofs[p & (BNODES - 1)], 1);
        srcIdx[pos] = (int)(p >> BSH);
    }
}

// ---------------- a0 = (X @ Wf) * dinv ; 2 nodes x 5 channels per thread ----------------
__global__ __launch_bounds__(256) void k_xw(const float* __restrict__ x, const float* __restrict__ Wf,
                                            const float* __restrict__ dinv,
                                            float* __restrict__ as_) {
    __shared__ float sWf[DI * CO];
    for (int i = threadIdx.x; i < DI * CO; i += blockDim.x) sWf[i] = Wf[i];
    __syncthreads();
    int gid = blockIdx.x * 256 + threadIdx.x;
    if (gid >= NN) return;
    int p = gid >> 1, c0 = (gid & 1) * 5;
    int n0 = 2 * p, n1 = n0 + 1;
    float a0[5] = {0, 0, 0, 0, 0}, a1[5] = {0, 0, 0, 0, 0};
    const float4* x0 = (const float4*)(x + (size_t)n0 * DI);
    const float4* x1 = (const float4*)(x + (size_t)n1 * DI);
#pragma unroll 4
    for (int d4 = 0; d4 < DI / 4; ++d4) {
        float4 u = x0[d4], v = x1[d4];
        const float* w = &sWf[d4 * 4 * CO + c0];
#pragma unroll
        for (int c = 0; c < 5; ++c) {
            float w0 = w[c], w1 = w[CO + c], w2 = w[2 * CO + c], w3 = w[3 * CO + c];
            a0[c] += u.x * w0 + u.y * w1 + u.z * w2 + u.w * w3;
            a1[c] += v.x * w0 + v.y * w1 + v.z * w2 + v.w * w3;
        }
    }
    float d0 = dinv[n0], d1 = dinv[n1];
    float* r0 = as_ + (size_t)n0 * PADF + c0;
    float* r1 = as_ + (size_t)n1 * PADF + c0;
#pragma unroll
    for (int c = 0; c < 5; ++c) {
        r0[c] = a0[c] * d0;
        r1[c] = a1[c] * d1;
    }
}

// ---------------- gather round: register accumulate + shfl reduce (LPN=4) ----------------
// src rows pre-scaled by dinv[src]; y = dinv[n]*(sum+self)+c; non-final pre-scale by dinv[n].
template <int FINAL>
__global__ __launch_bounds__(256) void k_gather(const int* __restrict__ rowptr_end,
                                                const int* __restrict__ srcIdx,
                                                const float* __restrict__ src,
                                                const float* __restrict__ dinv,
                                                const float* __restrict__ cvec, int coff,
                                                float* __restrict__ dst) {
    int gid = blockIdx.x * 256 + threadIdx.x;
    int n = gid >> 2;
    int l = threadIdx.x & (LPN - 1);
    if (n >= NN) return;
    int beg = (n == 0) ? 0 : rowptr_end[n - 1];
    int end = rowptr_end[n];
    float acc[CO];
#pragma unroll
    for (int c = 0; c < CO; ++c) acc[c] = 0.f;
    for (int e = beg + l; e < end; e += LPN) {
        int s = __builtin_nontemporal_load(&srcIdx[e]);
        const float* sp = src + (size_t)s * PADF;
        float4 a = ((const float4*)sp)[0];
        float4 b = ((const float4*)sp)[1];
        float2 c2 = ((const float2*)(sp + 8))[0];
        acc[0] += a.x; acc[1] += a.y; acc[2] += a.z; acc[3] += a.w;
        acc[4] += b.x; acc[5] += b.y; acc[6] += b.z; acc[7] += b.w;
        acc[8] += c2.x; acc[9] += c2.y;
    }
#pragma unroll
    for (int m = 1; m < LPN; m <<= 1) {
#pragma unroll
        for (int c = 0; c < CO; ++c) acc[c] += __shfl_xor(acc[c], m, 64);
    }
    if (l == 0) {
        float di = dinv[n];
        const float* selfp = src + (size_t)n * PADF;
        float o[CO];
#pragma unroll
        for (int c = 0; c < CO; ++c) {
            float y = di * (acc[c] + selfp[c]) + cvec[coff + c];
            o[c] = FINAL ? y : y * di;
        }
        float* dp = dst + (size_t)n * PADF;
        ((float4*)dp)[0] = make_float4(o[0], o[1], o[2], o[3]);
        ((float4*)dp)[1] = make_float4(o[4], o[5], o[6], o[7]);
        ((float2*)(dp + 8))[0] = make_float2(o[8], o[9]);
    }
}

// ---------------- mean-pool per graph + bl; one wave per graph ----------------
__global__ __launch_bounds__(64) void k_pool(const float* __restrict__ h,
                                             const int* __restrict__ gstart,
                                             const float* __restrict__ bl,
                                             float* __restrict__ out) {
    int g = blockIdx.x;
    int beg = gstart[g], end = gstart[g + 1];
    int l = threadIdx.x;
    float acc[CO];
#pragma unroll
    for (int c = 0; c < CO; ++c) acc[c] = 0.f;
    for (int n = beg + l; n < end; n += 64) {
        const float* sp = h + (size_t)n * PADF;
        float4 a = ((const float4*)sp)[0];
        float4 b = ((const float4*)sp)[1];
        float2 c2 = ((const float2*)(sp + 8))[0];
        acc[0] += a.x; acc[1] += a.y; acc[2] += a.z; acc[3] += a.w;
        acc[4] += b.x; acc[5] += b.y; acc[6] += b.z; acc[7] += b.w;
        acc[8] += c2.x; acc[9] += c2.y;
    }
#pragma unroll
    for (int m = 1; m < 64; m <<= 1) {
#pragma unroll
        for (int c = 0; c < CO; ++c) acc[c] += __shfl_xor(acc[c], m, 64);
    }
    if (l == 0) {
        float cf = fmaxf((float)(end - beg), 1.f);
#pragma unroll
        for (int c = 0; c < CO; ++c) out[(size_t)g * CO + c] = acc[c] / cf + bl[c];
    }
}

extern "C" void kernel_launch(void* const* d_in, const int* in_sizes, int n_in,
                              void* d_out, int out_size, void* d_ws, size_t ws_size,
                              hipStream_t stream) {
    const float* x    = (const float*)d_in[0];
    const int*   ei   = (const int*)d_in[1];
    const int*   batch= (const int*)d_in[2];
    const float* W1   = (const float*)d_in[3];
    const float* b1   = (const float*)d_in[4];
    const float* W2   = (const float*)d_in[5];
    const float* b2   = (const float*)d_in[6];
    const float* W3   = (const float*)d_in[7];
    const float* b3   = (const float*)d_in[8];
    const float* Wl   = (const float*)d_in[9];
    const float* bl   = (const float*)d_in[10];
    float* out = (float*)d_out;

    const int* row = ei;        // edge_index[0]
    const int* col = ei + EE;   // edge_index[1]

    float* ws = (float*)d_ws;
    size_t off = 0;
    auto alloc = [&](size_t elems) { size_t cur = off; off += (elems + 63) & ~(size_t)63; return cur; };
    float*    Wf      = ws + alloc(DI * CO);
    float*    cvec    = ws + alloc(3 * CO);
    float*    dinv    = ws + alloc(NN);
    int*      S       = (int*)(ws + alloc(SN));
    int*      bsum    = (int*)(ws + alloc(128));
    unsigned* ebuf    = (unsigned*)(ws + alloc(EE));
    int*      srcIdx  = (int*)(ws + alloc(EE));
    int*      rowptr  = (int*)(ws + alloc(NN));
    float*    as_     = ws + alloc((size_t)NN * PADF);
    float*    bbuf    = ws + alloc((size_t)NN * PADF);
    int*      gstart  = (int*)(ws + alloc(GG + 1));
    (void)ws_size; (void)in_sizes; (void)n_in; (void)out_size;

    const int BT = 256;
    int gN = (NN + BT - 1) / BT;
    int gNL = ((NN * LPN) + BT - 1) / BT;
    int gFront = NT + 1 + (GG + 1 + BT - 1) / BT;

    hipLaunchKernelGGL(k_front,    dim3(gFront), dim3(256), 0, stream,
                       col, W1, W2, W3, Wl, b1, b2, b3, batch, S, Wf, cvec, gstart);
    hipLaunchKernelGGL(k_scanA,    dim3(NSB), dim3(SCB), 0, stream, S, bsum);
    hipLaunchKernelGGL(k_scanB,    dim3(1),   dim3(128), 0, stream, bsum);
    hipLaunchKernelGGL(k_scanC,    dim3(NSB), dim3(SCB), 0, stream, S, bsum);
    hipLaunchKernelGGL(k_pscatter, dim3(NT),  dim3(256), 0, stream, row, col, S, ebuf);
    hipLaunchKernelGGL(k_bsort,    dim3(NB),  dim3(256), 0, stream, ebuf, S, srcIdx, rowptr, dinv);
    hipLaunchKernelGGL(k_xw,       dim3(gN),  dim3(BT), 0, stream, x, Wf, dinv, as_);

    hipLaunchKernelGGL((k_gather<0>), dim3(gNL), dim3(BT), 0, stream, rowptr, srcIdx, as_,  dinv, cvec, 0,      bbuf);
    hipLaunchKernelGGL((k_gather<0>), dim3(gNL), dim3(BT), 0, stream, rowptr, srcIdx, bbuf, dinv, cvec, CO,     as_);
    hipLaunchKernelGGL((k_gather<1>), dim3(gNL), dim3(BT), 0, stream, rowptr, srcIdx, as_,  dinv, cvec, 2 * CO, bbuf);

    hipLaunchKernelGGL(k_pool, dim3(GG), dim3(64), 0, stream, bbuf, gstart, bl, out);
}

// Round 10
// 277.809 us; speedup vs baseline: 1.8988x; 1.0213x over previous
//
#include <hip/hip_runtime.h>

#define NN 100000
#define EE 1600000
#define DI 128
#define HH 64
#define CO 10
#define PADF 16                             // floats per staged row (64B, line-aligned)
#define GG 1024
#define BSH 7                               // 128 nodes per bucket
#define BNODES (1 << BSH)
#define NB ((NN + BNODES - 1) / BNODES)     // 782 buckets
#define TILE 4096
#define NT ((EE + TILE - 1) / TILE)         // 391 tiles
#define SN (NB * NT)                        // (bucket,tile) counters = 305,762
#define SCB 1024
#define NSB ((SN + SCB - 1) / SCB)          // 299 scan blocks
#define LPN 4                               // lanes per node in gather

// ---- fused front: blocks [0,NT) bucket-histogram; block NT collapsed weights; rest gstart ----
__global__ __launch_bounds__(256) void k_front(const int* __restrict__ col,
                                               const float* __restrict__ W1, const float* __restrict__ W2,
                                               const float* __restrict__ W3, const float* __restrict__ Wl,
                                               const float* __restrict__ b1, const float* __restrict__ b2,
                                               const float* __restrict__ b3,
                                               const int* __restrict__ batch,
                                               int* __restrict__ cnt, float* __restrict__ Wf,
                                               float* __restrict__ cvec, int* __restrict__ gstart) {
    __shared__ float smem[1280];
    int bid = blockIdx.x, t = threadIdx.x;
    if (bid < NT) {
        int* h = (int*)smem;
        for (int i = t; i < NB; i += 256) h[i] = 0;
        __syncthreads();
        int base = bid * TILE, end = min(base + TILE, EE);
        for (int e = base + t; e < end; e += 256)
            atomicAdd(&h[__builtin_nontemporal_load(&col[e]) >> BSH], 1);
        __syncthreads();
        for (int i = t; i < NB; i += 256) cnt[i * NT + bid] = h[i];
    } else if (bid == NT) {
        float* M3l = smem;           // 640
        float* M23l = smem + 640;    // 640
        for (int i = t; i < HH * CO; i += 256) {
            int r = i / CO, c = i % CO;
            float s = 0.f;
            for (int k = 0; k < HH; ++k) s += W3[r * HH + k] * Wl[k * CO + c];
            M3l[i] = s;
        }
        __syncthreads();
        for (int i = t; i < HH * CO; i += 256) {
            int r = i / CO, c = i % CO;
            float s = 0.f;
            for (int k = 0; k < HH; ++k) s += W2[r * HH + k] * M3l[k * CO + c];
            M23l[i] = s;
        }
        __syncthreads();
        for (int i = t; i < DI * CO; i += 256) {
            int r = i / CO, c = i % CO;
            float s = 0.f;
            for (int k = 0; k < HH; ++k) s += W1[r * HH + k] * M23l[k * CO + c];
            Wf[i] = s;
        }
        if (t < CO) {
            float s1 = 0.f, s2 = 0.f, s3 = 0.f;
            for (int k = 0; k < HH; ++k) {
                s1 += b1[k] * M23l[k * CO + t];
                s2 += b2[k] * M3l[k * CO + t];
                s3 += b3[k] * Wl[k * CO + t];
            }
            cvec[t] = s1; cvec[CO + t] = s2; cvec[2 * CO + t] = s3;
        }
    } else {
        int g = (bid - NT - 1) * 256 + t;
        if (g <= GG) {
            int lo = 0, hi = NN;
            while (lo < hi) { int mid = (lo + hi) >> 1; if (batch[mid] < g) lo = mid + 1; else hi = mid; }
            gstart[g] = lo;
        }
    }
}

// ---------------- scanA: per-block exclusive scan, block totals to bsum ----------------
__global__ __launch_bounds__(SCB) void k_scanA(int* __restrict__ a, int* __restrict__ bsum) {
    __shared__ int s[SCB];
    int t = threadIdx.x, idx = blockIdx.x * SCB + t;
    int v = (idx < SN) ? a[idx] : 0;
    s[t] = v;
    __syncthreads();
    for (int off = 1; off < SCB; off <<= 1) {
        int u = (t >= off) ? s[t - off] : 0;
        __syncthreads();
        s[t] += u;
        __syncthreads();
    }
    if (idx < SN) a[idx] = s[t] - v;
    if (t == SCB - 1) bsum[blockIdx.x] = s[t];
}
// ---------------- scanC: block offset = reduce(bsum[0..bid)) ; add ----------------
__global__ __launch_bounds__(SCB) void k_scanC(int* __restrict__ a, const int* __restrict__ bsum) {
    __shared__ int red[SCB];
    int t = threadIdx.x, bid = blockIdx.x;
    int partial = 0;
    for (int i = t; i < bid; i += SCB) partial += bsum[i];
    red[t] = partial;
    __syncthreads();
    for (int off = SCB / 2; off > 0; off >>= 1) {
        if (t < off) red[t] += red[t + off];
        __syncthreads();
    }
    int idx = bid * SCB + t;
    if (idx < SN) a[idx] += red[0];
}

// ---------------- scatter edges bucket-major; packed (row<<7)|(col&127) ----------------
__global__ __launch_bounds__(256) void k_pscatter(const int* __restrict__ row, const int* __restrict__ col,
                                                  const int* __restrict__ S, unsigned* __restrict__ ebuf) {
    __shared__ int ofs[NB];
    for (int i = threadIdx.x; i < NB; i += 256) ofs[i] = S[i * NT + blockIdx.x];
    __syncthreads();
    int base = blockIdx.x * TILE;
    int end = min(base + TILE, EE);
    for (int e = base + threadIdx.x; e < end; e += 256) {
        int c = __builtin_nontemporal_load(&col[e]);
        int r = __builtin_nontemporal_load(&row[e]);
        int pos = atomicAdd(&ofs[c >> BSH], 1);
        ebuf[pos] = ((unsigned)r << BSH) | (unsigned)(c & (BNODES - 1));
    }
}

// ---------------- per-bucket counting sort -> CSR + dinv (zero global atomics) ----------------
__global__ __launch_bounds__(256) void k_bsort(const unsigned* __restrict__ ebuf, const int* __restrict__ S,
                                               int* __restrict__ srcIdx, int* __restrict__ rowptr_end,
                                               float* __restrict__ dinv) {
    __shared__ int cnt[BNODES];
    __shared__ int s[BNODES];
    __shared__ int ofs[BNODES];
    int t = threadIdx.x;
    int b = blockIdx.x;
    if (t < BNODES) cnt[t] = 0;
    __syncthreads();
    int beg = S[b * NT];
    int end = (b + 1 < NB) ? S[(b + 1) * NT] : EE;
    for (int e = beg + t; e < end; e += 256)
        atomicAdd(&cnt[__builtin_nontemporal_load(&ebuf[e]) & (BNODES - 1)], 1);
    __syncthreads();
    int v = 0;
    if (t < BNODES) { v = cnt[t]; s[t] = v; }
    __syncthreads();
    for (int off = 1; off < BNODES; off <<= 1) {
        int u = 0;
        if (t < BNODES && t >= off) u = s[t - off];
        __syncthreads();
        if (t < BNODES) s[t] += u;
        __syncthreads();
    }
    if (t < BNODES) {
        int n = (b << BSH) + t;
        if (n < NN) {
            dinv[n] = rsqrtf((float)(v + 1));        // +1 self loop
            rowptr_end[n] = beg + s[t];              // inclusive end
        }
        ofs[t] = beg + s[t] - v;                     // exclusive start
    }
    __syncthreads();
    for (int e = beg + t; e < end; e += 256) {
        unsigned p = __builtin_nontemporal_load(&ebuf[e]);
        int pos = atomicAdd(&ofs[p & (BNODES - 1)], 1);
        srcIdx[pos] = (int)(p >> BSH);
    }
}

// ---------------- a0 = (X @ Wf) * dinv ; 2 nodes x 5 channels per thread ----------------
__global__ __launch_bounds__(256) void k_xw(const float* __restrict__ x, const float* __restrict__ Wf,
                                            const float* __restrict__ dinv,
                                            float* __restrict__ as_) {
    __shared__ float sWf[DI * CO];
    for (int i = threadIdx.x; i < DI * CO; i += blockDim.x) sWf[i] = Wf[i];
    __syncthreads();
    int gid = blockIdx.x * 256 + threadIdx.x;
    if (gid >= NN) return;
    int p = gid >> 1, c0 = (gid & 1) * 5;
    int n0 = 2 * p, n1 = n0 + 1;
    float a0[5] = {0, 0, 0, 0, 0}, a1[5] = {0, 0, 0, 0, 0};
    const float4* x0 = (const float4*)(x + (size_t)n0 * DI);
    const float4* x1 = (const float4*)(x + (size_t)n1 * DI);
#pragma unroll 4
    for (int d4 = 0; d4 < DI / 4; ++d4) {
        float4 u = x0[d4], v = x1[d4];
        const float* w = &sWf[d4 * 4 * CO + c0];
#pragma unroll
        for (int c = 0; c < 5; ++c) {
            float w0 = w[c], w1 = w[CO + c], w2 = w[2 * CO + c], w3 = w[3 * CO + c];
            a0[c] += u.x * w0 + u.y * w1 + u.z * w2 + u.w * w3;
            a1[c] += v.x * w0 + v.y * w1 + v.z * w2 + v.w * w3;
        }
    }
    float d0 = dinv[n0], d1 = dinv[n1];
    float* r0 = as_ + (size_t)n0 * PADF + c0;
    float* r1 = as_ + (size_t)n1 * PADF + c0;
#pragma unroll
    for (int c = 0; c < 5; ++c) {
        r0[c] = a0[c] * d0;
        r1[c] = a1[c] * d1;
    }
}

// ---------------- gather round: register accumulate + shfl reduce (LPN=4) ----------------
// src rows pre-scaled by dinv[src]; y = dinv[n]*(sum+self)+c; non-final pre-scale by dinv[n].
template <int FINAL>
__global__ __launch_bounds__(256) void k_gather(const int* __restrict__ rowptr_end,
                                                const int* __restrict__ srcIdx,
                                                const float* __restrict__ src,
                                                const float* __restrict__ dinv,
                                                const float* __restrict__ cvec, int coff,
                                                float* __restrict__ dst) {
    int gid = blockIdx.x * 256 + threadIdx.x;
    int n = gid >> 2;
    int l = threadIdx.x & (LPN - 1);
    if (n >= NN) return;
    int beg = (n == 0) ? 0 : rowptr_end[n - 1];
    int end = rowptr_end[n];
    float acc[CO];
#pragma unroll
    for (int c = 0; c < CO; ++c) acc[c] = 0.f;
    for (int e = beg + l; e < end; e += LPN) {
        int s = __builtin_nontemporal_load(&srcIdx[e]);
        const float* sp = src + (size_t)s * PADF;
        float4 a = ((const float4*)sp)[0];
        float4 b = ((const float4*)sp)[1];
        float2 c2 = ((const float2*)(sp + 8))[0];
        acc[0] += a.x; acc[1] += a.y; acc[2] += a.z; acc[3] += a.w;
        acc[4] += b.x; acc[5] += b.y; acc[6] += b.z; acc[7] += b.w;
        acc[8] += c2.x; acc[9] += c2.y;
    }
#pragma unroll
    for (int m = 1; m < LPN; m <<= 1) {
#pragma unroll
        for (int c = 0; c < CO; ++c) acc[c] += __shfl_xor(acc[c], m, 64);
    }
    if (l == 0) {
        float di = dinv[n];
        const float* selfp = src + (size_t)n * PADF;
        float o[CO];
#pragma unroll
        for (int c = 0; c < CO; ++c) {
            float y = di * (acc[c] + selfp[c]) + cvec[coff + c];
            o[c] = FINAL ? y : y * di;
        }
        float* dp = dst + (size_t)n * PADF;
        ((float4*)dp)[0] = make_float4(o[0], o[1], o[2], o[3]);
        ((float4*)dp)[1] = make_float4(o[4], o[5], o[6], o[7]);
        ((float2*)(dp + 8))[0] = make_float2(o[8], o[9]);
    }
}

// ---------------- mean-pool per graph + bl; one wave per graph ----------------
__global__ __launch_bounds__(64) void k_pool(const float* __restrict__ h,
                                             const int* __restrict__ gstart,
                                             const float* __restrict__ bl,
                                             float* __restrict__ out) {
    int g = blockIdx.x;
    int beg = gstart[g], end = gstart[g + 1];
    int l = threadIdx.x;
    float acc[CO];
#pragma unroll
    for (int c = 0; c < CO; ++c) acc[c] = 0.f;
    for (int n = beg + l; n < end; n += 64) {
        const float* sp = h + (size_t)n * PADF;
        float4 a = ((const float4*)sp)[0];
        float4 b = ((const float4*)sp)[1];
        float2 c2 = ((const float2*)(sp + 8))[0];
        acc[0] += a.x; acc[1] += a.y; acc[2] += a.z; acc[3] += a.w;
        acc[4] += b.x; acc[5] += b.y; acc[6] += b.z; acc[7] += b.w;
        acc[8] += c2.x; acc[9] += c2.y;
    }
#pragma unroll
    for (int m = 1; m < 64; m <<= 1) {
#pragma unroll
        for (int c = 0; c < CO; ++c) acc[c] += __shfl_xor(acc[c], m, 64);
    }
    if (l == 0) {
        float cf = fmaxf((float)(end - beg), 1.f);
#pragma unroll
        for (int c = 0; c < CO; ++c) out[(size_t)g * CO + c] = acc[c] / cf + bl[c];
    }
}

extern "C" void kernel_launch(void* const* d_in, const int* in_sizes, int n_in,
                              void* d_out, int out_size, void* d_ws, size_t ws_size,
                              hipStream_t stream) {
    const float* x    = (const float*)d_in[0];
    const int*   ei   = (const int*)d_in[1];
    const int*   batch= (const int*)d_in[2];
    const float* W1   = (const float*)d_in[3];
    const float* b1   = (const float*)d_in[4];
    const float* W2   = (const float*)d_in[5];
    const float* b2   = (const float*)d_in[6];
    const float* W3   = (const float*)d_in[7];
    const float* b3   = (const float*)d_in[8];
    const float* Wl   = (const float*)d_in[9];
    const float* bl   = (const float*)d_in[10];
    float* out = (float*)d_out;

    const int* row = ei;        // edge_index[0]
    const int* col = ei + EE;   // edge_index[1]

    float* ws = (float*)d_ws;
    size_t off = 0;
    auto alloc = [&](size_t elems) { size_t cur = off; off += (elems + 63) & ~(size_t)63; return cur; };
    float*    Wf      = ws + alloc(DI * CO);
    float*    cvec    = ws + alloc(3 * CO);
    float*    dinv    = ws + alloc(NN);
    int*      S       = (int*)(ws + alloc(SN));
    int*      bsum    = (int*)(ws + alloc(NSB + 64));
    unsigned* ebuf    = (unsigned*)(ws + alloc(EE));
    int*      srcIdx  = (int*)(ws + alloc(EE));
    int*      rowptr  = (int*)(ws + alloc(NN));
    float*    as_     = ws + alloc((size_t)NN * PADF);
    float*    bbuf    = ws + alloc((size_t)NN * PADF);
    int*      gstart  = (int*)(ws + alloc(GG + 1));
    (void)ws_size; (void)in_sizes; (void)n_in; (void)out_size;

    const int BT = 256;
    int gN = (NN + BT - 1) / BT;
    int gNL = ((NN * LPN) + BT - 1) / BT;
    int gFront = NT + 1 + (GG + 1 + BT - 1) / BT;

    hipLaunchKernelGGL(k_front,    dim3(gFront), dim3(256), 0, stream,
                       col, W1, W2, W3, Wl, b1, b2, b3, batch, S, Wf, cvec, gstart);
    hipLaunchKernelGGL(k_scanA,    dim3(NSB), dim3(SCB), 0, stream, S, bsum);
    hipLaunchKernelGGL(k_scanC,    dim3(NSB), dim3(SCB), 0, stream, S, bsum);
    hipLaunchKernelGGL(k_pscatter, dim3(NT),  dim3(256), 0, stream, row, col, S, ebuf);
    hipLaunchKernelGGL(k_bsort,    dim3(NB),  dim3(256), 0, stream, ebuf, S, srcIdx, rowptr, dinv);
    hipLaunchKernelGGL(k_xw,       dim3(gN),  dim3(BT), 0, stream, x, Wf, dinv, as_);

    hipLaunchKernelGGL((k_gather<0>), dim3(gNL), dim3(BT), 0, stream, rowptr, srcIdx, as_,  dinv, cvec, 0,      bbuf);
    hipLaunchKernelGGL((k_gather<0>), dim3(gNL), dim3(BT), 0, stream, rowptr, srcIdx, bbuf, dinv, cvec, CO,     as_);
    hipLaunchKernelGGL((k_gather<1>), dim3(gNL), dim3(BT), 0, stream, rowptr, srcIdx, as_,  dinv, cvec, 2 * CO, bbuf);

    hipLaunchKernelGGL(k_pool, dim3(GG), dim3(64), 0, stream, bbuf, gstart, bl, out);
}